// Round 8
// baseline (407.217 us; speedup 1.0000x reference)
//
#include <hip/hip_runtime.h>
#include <math.h>

#define B_   4
#define S_   4096
#define D_   1024
#define HD_  64

// ---------------- split-K flash constants ----------------
#define CK            8          // k-tiles (of 64 keys) per chunk
#define CHUNKS_PER_B  288        // sum_{qi=0}^{63} (qi/8 + 1)  (partial slots)
#define FULL_CHUNKS   224        // sum_{qi=0}^{63} (qi/8)      (8-iter chunks/batch)
// partials stored as bf16 (o[64]) + fp32 m,l -> 72 shorts (144 B) per row
#define PSTRIDE_SH    72         // shorts per row in a partial slot
#define SLOT_SH       (64 * PSTRIDE_SH)

// LESSONS LEDGER:
//  - R2: defer-max (T13) PERMANENTLY REVERTED (post-timing divergence).
//  - R5: hipLaunchCooperativeKernel dead under harness graph capture.
//  - R7 MEASUREMENT: T_pipeline = 62.1 us, fixed harness overhead = 91.3 us
//    (60% of dur_us is untouchable). Kernel model underestimates 2x.
//  - R8 = SURFACING ROUND: proj body x4, flash body x8 INSIDE their
//    dispatches (idempotent reps) so they exceed the 41 us fills and
//    appear in top-5 WITH counters. dur_R8 is a throwaway number.
//    T_proj = proj_dispatch/4, T_flash = flash_dispatch/8.
#define QSCALE   (0.125f * 1.44269504089f)

#define PROJ_REP   4             // R8 instrumentation — revert to 1 in R9
#define FLASH_REP  8             // R8 instrumentation — revert to 1 in R9

typedef float  f32x4  __attribute__((ext_vector_type(4)));
typedef __bf16 bf16x8 __attribute__((ext_vector_type(8)));
typedef __bf16 bf16x4 __attribute__((ext_vector_type(4)));

static __device__ __forceinline__ unsigned short bfbits(float f) {
    __bf16 h = (__bf16)f;
    return __builtin_bit_cast(unsigned short, h);
}

// hardware exp2: llvm.exp2.f32 lowers to a single v_exp_f32. exp2(-inf) = 0.
static __device__ __forceinline__ float exp2_hw(float x) {
    return __builtin_exp2f(x);
}

// slot index of (qi, c) within a batch: qi + sum_{j<qi}(j>>3) + c
static __device__ __forceinline__ int chunk_slot(int qi, int c) {
    const int a = qi >> 3, r = qi & 7;
    return qi + 4 * a * (a - 1) + a * r + c;
}

// ------------------------------------------------------------------
// Kernel 0: convert wq/wk/wv (fp32 [64][1024]) into wbf (bf16 [192][1024]).
// ------------------------------------------------------------------
__global__ __launch_bounds__(256) void convert_w(
    const float* __restrict__ wq, const float* __restrict__ wk,
    const float* __restrict__ wv, unsigned short* __restrict__ wbf)
{
    const int col = blockIdx.x;            // 0..191
    const int p = col >> 6, h = col & 63;
    const float* src = (p == 0 ? wq : (p == 1 ? wk : wv)) + (size_t)h * D_;
    const int t = threadIdx.x;
    const float4 v = ((const float4*)src)[t];
    bf16x4 o;
    o[0] = (__bf16)v.x; o[1] = (__bf16)v.y; o[2] = (__bf16)v.z; o[3] = (__bf16)v.w;
    *(bf16x4*)&wbf[(size_t)col * D_ + 4 * t] = o;
}

// ------------------------------------------------------------------
// Kernel 1: QKV projection via bf16 MFMA (16x16x32), BK=128.
// R6 body, internally repeated PROJ_REP times (R8 surfacing).
// ------------------------------------------------------------------
__global__ __launch_bounds__(256) void proj_mfma(
    const float* __restrict__ x, const unsigned short* __restrict__ wbf,
    const float* __restrict__ bq, const float* __restrict__ bk,
    const float* __restrict__ bv,
    unsigned short* __restrict__ qbf, unsigned short* __restrict__ kbf,
    unsigned short* __restrict__ vtb)
{
    __shared__ unsigned short xs[32][136];    // 8704 B
    __shared__ unsigned short wsh[96][136];   // 26112 B

    const int t = threadIdx.x;
    const int w = t >> 6, lane = t & 63;
    const int n = lane & 15, g = lane >> 4;
    const int koff = 8 * g;
    const int rt = w & 1, cg = w >> 1;
    const size_t row0 = (size_t)blockIdx.x * 32;
    const int colbase = 96 * blockIdx.y;

    for (int rep = 0; rep < PROJ_REP; ++rep) {
        f32x4 acc[3];
#pragma unroll
        for (int i = 0; i < 3; ++i) acc[i] = (f32x4)0.f;

        for (int chunk = 0; chunk < 8; ++chunk) {
            const int d0 = chunk * 128;
            __syncthreads();
            // stage x: 32 rows x 128 d, fp32 -> bf16 (4 float4/thread)
#pragma unroll
            for (int i = 0; i < 4; ++i) {
                int e = t + i * 256;              // 0..1023 float4
                int r = e >> 5, c4 = (e & 31) * 4;
                float4 v = *(const float4*)&x[(row0 + r) * D_ + d0 + c4];
                bf16x4 o;
                o[0] = (__bf16)v.x; o[1] = (__bf16)v.y;
                o[2] = (__bf16)v.z; o[3] = (__bf16)v.w;
                *(bf16x4*)&xs[r][c4] = o;
            }
            // stage w: 96 cols x 128 d bf16 (6 uint4/thread)
#pragma unroll
            for (int i = 0; i < 6; ++i) {
                int e = t + i * 256;              // 0..1535
                int col = e >> 4, g8 = (e & 15) * 8;
                uint4 v = *(const uint4*)&wbf[(size_t)(colbase + col) * D_ + d0 + g8];
                *(uint4*)&wsh[col][g8] = v;
            }
            __syncthreads();

#pragma unroll
            for (int ks = 0; ks < 4; ++ks) {
                const int k0 = 32 * ks;
                const bf16x8 a = *(const bf16x8*)&xs[16 * rt + n][k0 + koff];
#pragma unroll
                for (int ci = 0; ci < 3; ++ci) {
                    const bf16x8 b = *(const bf16x8*)&wsh[48 * cg + 16 * ci + n][k0 + koff];
                    acc[ci] = __builtin_amdgcn_mfma_f32_16x16x32_bf16(a, b, acc[ci], 0, 0, 0);
                }
            }
        }

#pragma unroll
        for (int ci = 0; ci < 3; ++ci) {
            const int gct = 6 * blockIdx.y + 3 * cg + ci;
            const int p = gct >> 2, h0 = (gct & 3) * 16;
            const int h = h0 + n;
            const float bb = (p == 0 ? bq : (p == 1 ? bk : bv))[h];
            if (p == 2) {
                const size_t grow0 = row0 + 16 * rt + 4 * g;
                const int bidx = (int)(grow0 >> 12);
                const int s0 = (int)(grow0 & 4095);
                bf16x4 u;
                u[0] = (__bf16)(acc[ci][0] + bb); u[1] = (__bf16)(acc[ci][1] + bb);
                u[2] = (__bf16)(acc[ci][2] + bb); u[3] = (__bf16)(acc[ci][3] + bb);
                *(bf16x4*)&vtb[((size_t)bidx * HD_ + h) * S_ + s0] = u;
            } else {
                unsigned short* outp = (p == 0 ? qbf : kbf);
                const float scale = (p == 0) ? QSCALE : 1.0f;
#pragma unroll
                for (int r = 0; r < 4; ++r) {
                    const size_t grow = row0 + 16 * rt + 4 * g + r;
                    outp[grow * HD_ + h] = bfbits((acc[ci][r] + bb) * scale);
                }
            }
        }
    }
}

// ------------------------------------------------------------------
// Kernel 2: split-K causal flash attention, bf16 MFMA. R6 body,
// internally repeated FLASH_REP times (R8 surfacing).
// ------------------------------------------------------------------
__global__ __launch_bounds__(256) void flash_splitk(
    const unsigned short* __restrict__ qg, const unsigned short* __restrict__ kg,
    const unsigned short* __restrict__ vt, float* __restrict__ out,
    unsigned short* __restrict__ part)
{
    __shared__ unsigned short qsh[64][72];      // 9216 B  Q rows (pre-scaled, log2e folded)
    __shared__ unsigned short ksh[64][72];      // 9216 B  K rows
    __shared__ unsigned short vsh[64][72];      // 9216 B  vT[h][key]
    __shared__ unsigned short psh[4][16][72];   // 9216 B  per-wave P[q][key]

    const int t    = threadIdx.x;
    const int w    = t >> 6;
    const int lane = t & 63;
    const int n    = lane & 15;      // MFMA col index
    const int g    = lane >> 4;      // MFMA row group
    const int koff = 8 * g;

    // decode blockIdx.x -> (b, qi, c), full chunks first (tail fill)
    int b, qi, c;
    {
        const int idx = blockIdx.x;
        if (idx < B_ * FULL_CHUNKS) {          // full 8-iteration chunks
            b = idx / FULL_CHUNKS;
            int rem = idx - b * FULL_CHUNKS;
            qi = 8;
            while (rem >= (qi >> 3)) { rem -= (qi >> 3); ++qi; }
            c = rem;
        } else {                               // last (partial) chunk of each qi
            const int r2 = idx - B_ * FULL_CHUNKS;
            b = r2 >> 6;
            qi = r2 & 63;
            c = qi >> 3;
        }
    }
    const int kt0 = c * CK;
    const int kt1 = min(qi, kt0 + CK - 1);
    const int nc  = (qi >> 3) + 1;

    const size_t qtile = ((size_t)b * S_ + (size_t)qi * 64) * HD_;

    // stage Q (once): 2 uint4/thread
    {
        const uint4* src = (const uint4*)(qg + qtile);
#pragma unroll
        for (int i = 0; i < 2; ++i) {
            int e = t + i * 256;                // 0..511
            int r = e >> 3, gg = e & 7;
            *(uint4*)&qsh[r][8 * gg] = src[e];
        }
    }

    // per-thread staging coordinates (e0 = t, e1 = t+256)
    const int r0s = t >> 3,        gg0 = t & 7;
    const int r1s = (t + 256) >> 3, gg1 = (t + 256) & 7;

    for (int rep = 0; rep < FLASH_REP; ++rep) {
        // T14 prologue: issue kt0's K/V global loads into registers
        uint4 kr0, kr1, vr0, vr1;
        {
            const size_t kvb = ((size_t)b * S_ + (size_t)kt0 * 64) * HD_;
            const uint4* ksrc = (const uint4*)(kg + kvb);
            kr0 = ksrc[t];
            kr1 = ksrc[t + 256];
            vr0 = *(const uint4*)&vt[((size_t)b * HD_ + r0s) * S_ + kt0 * 64 + 8 * gg0];
            vr1 = *(const uint4*)&vt[((size_t)b * HD_ + r1s) * S_ + kt0 * 64 + 8 * gg1];
        }

        f32x4 o4[4];                                 // O^T[h=16ht+4g+r][q=n]
#pragma unroll
        for (int i = 0; i < 4; ++i) o4[i] = (f32x4)0.f;
        float m_r = -INFINITY, l_r = 0.f;            // state of q = 16w+n (log2 domain)

        for (int kt = kt0; kt <= kt1; ++kt) {
            __syncthreads();                        // prev reads done (covers qsh + prev rep)
            // write the in-flight registers (compiler inserts vmcnt wait here)
            *(uint4*)&ksh[r0s][8 * gg0] = kr0;
            *(uint4*)&ksh[r1s][8 * gg1] = kr1;
            *(uint4*)&vsh[r0s][8 * gg0] = vr0;
            *(uint4*)&vsh[r1s][8 * gg1] = vr1;
            __syncthreads();

            // T14: issue NEXT tile's loads now; latency hides under this tile's compute
            if (kt < kt1) {
                const size_t kvb = ((size_t)b * S_ + (size_t)(kt + 1) * 64) * HD_;
                const uint4* ksrc = (const uint4*)(kg + kvb);
                kr0 = ksrc[t];
                kr1 = ksrc[t + 256];
                vr0 = *(const uint4*)&vt[((size_t)b * HD_ + r0s) * S_ + (kt + 1) * 64 + 8 * gg0];
                vr1 = *(const uint4*)&vt[((size_t)b * HD_ + r1s) * S_ + (kt + 1) * 64 + 8 * gg1];
            }

            // ---- S^T = K . Q^T : 4 m-tiles (keys) x 16 q (col = q = n) ----
            f32x4 sc[4];
#pragma unroll
            for (int mt = 0; mt < 4; ++mt) sc[mt] = (f32x4)0.f;
#pragma unroll
            for (int ks = 0; ks < 2; ++ks) {
                const bf16x8 bq8 = *(const bf16x8*)&qsh[16 * w + n][32 * ks + koff];
#pragma unroll
                for (int mt = 0; mt < 4; ++mt) {
                    const bf16x8 ak = *(const bf16x8*)&ksh[16 * mt + n][32 * ks + koff];
                    sc[mt] = __builtin_amdgcn_mfma_f32_16x16x32_bf16(ak, bq8, sc[mt], 0, 0, 0);
                }
            }

            // ---- causal mask (diagonal k-tile only) ----
            if (kt == qi) {
                const int qloc = 16 * w + n;
#pragma unroll
                for (int mt = 0; mt < 4; ++mt)
#pragma unroll
                    for (int r = 0; r < 4; ++r) {
                        const int kloc = 16 * mt + 4 * g + r;
                        if (kloc > qloc) sc[mt][r] = -INFINITY;
                    }
            }

            // ---- online softmax per column q (exp2 domain, always-rescale) ----
            float mx = -INFINITY;
#pragma unroll
            for (int mt = 0; mt < 4; ++mt)
#pragma unroll
                for (int r = 0; r < 4; ++r) mx = fmaxf(mx, sc[mt][r]);
            mx = fmaxf(mx, __shfl_xor(mx, 16));
            mx = fmaxf(mx, __shfl_xor(mx, 32));

            const float m_new = fmaxf(m_r, mx);
            const float alpha = exp2_hw(m_r - m_new);   // first iter: exp2(-inf)=0
            float psum = 0.f;
#pragma unroll
            for (int mt = 0; mt < 4; ++mt)
#pragma unroll
                for (int r = 0; r < 4; ++r) {
                    const float pe = exp2_hw(sc[mt][r] - m_new);
                    sc[mt][r] = pe;
                    psum += pe;
                }
            psum += __shfl_xor(psum, 16);
            psum += __shfl_xor(psum, 32);
            l_r = l_r * alpha + psum;
            m_r = m_new;

            // rescale O (all regs have col q = n -> alpha is in-lane)
#pragma unroll
            for (int ht = 0; ht < 4; ++ht)
#pragma unroll
                for (int r = 0; r < 4; ++r) o4[ht][r] *= alpha;

            // ---- pack P^T -> per-wave LDS p[q][key] (v_cvt_pk_bf16_f32) ----
#pragma unroll
            for (int mt = 0; mt < 4; ++mt) {
                bf16x4 u;
                u[0] = (__bf16)sc[mt][0]; u[1] = (__bf16)sc[mt][1];
                u[2] = (__bf16)sc[mt][2]; u[3] = (__bf16)sc[mt][3];
                *(bf16x4*)&psh[w][n][16 * mt + 4 * g] = u;
            }
            // same-wave RAW on LDS: compiler inserts lgkmcnt wait; no barrier needed

            // ---- O^T += vT . P^T  (A = vT rows, B = P^T; same LDS reads) ----
#pragma unroll
            for (int ks = 0; ks < 2; ++ks) {
                const bf16x8 ap = *(const bf16x8*)&psh[w][n][32 * ks + koff];
#pragma unroll
                for (int ht = 0; ht < 4; ++ht) {
                    const bf16x8 av = *(const bf16x8*)&vsh[16 * ht + n][32 * ks + koff];
                    o4[ht] = __builtin_amdgcn_mfma_f32_16x16x32_bf16(av, ap, o4[ht], 0, 0, 0);
                }
            }
        }

        const size_t qbase = ((size_t)b * S_ + (size_t)qi * 64) * HD_;
        if (nc == 1) {
            const float inv = 1.f / l_r;             // in-lane (q = 16w+n)
            const size_t ob = qbase + (size_t)(16 * w + n) * HD_;
#pragma unroll
            for (int ht = 0; ht < 4; ++ht) {
                float4 rv;
                rv.x = o4[ht][0] * inv; rv.y = o4[ht][1] * inv;
                rv.z = o4[ht][2] * inv; rv.w = o4[ht][3] * inv;
                *(float4*)&out[ob + 16 * ht + 4 * g] = rv;
            }
        } else {
            // partial slot row (q = 16w+n): o[64] bf16, then m,l fp32 at shorts 64/66
            const size_t sb = ((size_t)b * CHUNKS_PER_B + chunk_slot(qi, c)) * SLOT_SH;
            const size_t pb = sb + (size_t)(16 * w + n) * PSTRIDE_SH;
#pragma unroll
            for (int ht = 0; ht < 4; ++ht) {
                bf16x4 u;
                u[0] = (__bf16)o4[ht][0]; u[1] = (__bf16)o4[ht][1];
                u[2] = (__bf16)o4[ht][2]; u[3] = (__bf16)o4[ht][3];
                *(bf16x4*)&part[pb + 16 * ht + 4 * g] = u;
            }
            if (g == 0) {
                *(float*)&part[pb + 64] = m_r;       // log2-domain running max
                *(float*)&part[pb + 66] = l_r;
            }
        }
    }
}

// ------------------------------------------------------------------
// Kernel 3: merge partials for qi >= CK.  grid (56, B, 4) — R4 exact.
// ------------------------------------------------------------------
__global__ __launch_bounds__(256) void combine(
    const unsigned short* __restrict__ part, float* __restrict__ out)
{
    const int t  = threadIdx.x;
    const int qr = t >> 2, tc = t & 3;
    const int qi = blockIdx.x + CK;          // 8..63
    const int b  = blockIdx.y;
    const int hq = blockIdx.z;               // 0..3 -> h block of 16
    const int nc = (qi >> 3) + 1;

    const size_t base0 = ((size_t)b * CHUNKS_PER_B + chunk_slot(qi, 0)) * SLOT_SH
                       + (size_t)qr * PSTRIDE_SH;

    float M = -INFINITY;
    for (int c0 = 0; c0 < nc; ++c0)
        M = fmaxf(M, *(const float*)&part[base0 + (size_t)c0 * SLOT_SH + 64]);

    float L = 0.f;
    float o[4];
#pragma unroll
    for (int j = 0; j < 4; ++j) o[j] = 0.f;

    const int ho = hq * 16 + tc * 4;         // this thread's 4 heads

    for (int c0 = 0; c0 < nc; ++c0) {
        const size_t sb = base0 + (size_t)c0 * SLOT_SH;
        const float m_c = *(const float*)&part[sb + 64];
        const float l_c = *(const float*)&part[sb + 66];
        const float w = exp2_hw(m_c - M);
        L += w * l_c;
        const bf16x4 ov = *(const bf16x4*)&part[sb + ho];
#pragma unroll
        for (int j = 0; j < 4; ++j) o[j] += w * (float)ov[j];
    }

    const float inv = 1.f / L;
    const size_t ob = ((size_t)b * S_ + (size_t)qi * 64 + qr) * HD_ + ho;
    float4 r;
    r.x = o[0] * inv; r.y = o[1] * inv; r.z = o[2] * inv; r.w = o[3] * inv;
    *(float4*)&out[ob] = r;
}

// ------------------------------------------------------------------
// R8 SURFACING ROUND: single pipeline, but proj/flash internally
// repeated (PROJ_REP/FLASH_REP) so their dispatches exceed the ~41 us
// harness fills and surface in rocprof top-5 WITH counters.
// T_proj = proj_dispatch_dur/4, T_flash = flash_dispatch_dur/8.
// dur_us this round is a throwaway number.
// ------------------------------------------------------------------
extern "C" void kernel_launch(void* const* d_in, const int* in_sizes, int n_in,
                              void* d_out, int out_size, void* d_ws, size_t ws_size,
                              hipStream_t stream)
{
    const float* x  = (const float*)d_in[0];
    const float* wq = (const float*)d_in[1];
    const float* bq = (const float*)d_in[2];
    const float* wk = (const float*)d_in[3];
    const float* bk = (const float*)d_in[4];
    const float* wv = (const float*)d_in[5];
    const float* bv = (const float*)d_in[6];
    float* outp = (float*)d_out;

    // ws layout: qbf | kbf | vt (bf16, n each) | wbf (bf16) | part (bf16+fp32 m,l)
    const size_t n = (size_t)B_ * S_ * HD_;        // 1048576
    unsigned short* qbf = (unsigned short*)d_ws;
    unsigned short* kbf = qbf + n;
    unsigned short* vtb = kbf + n;
    unsigned short* wbf = vtb + n;                 // 192*1024 bf16
    unsigned short* part = wbf + (size_t)192 * D_; // 4*288*4608 shorts = 10.6 MB

    convert_w<<<dim3(192), 256, 0, stream>>>(wq, wk, wv, wbf);
    proj_mfma<<<dim3(B_ * S_ / 32, 2), 256, 0, stream>>>(
        x, wbf, bq, bk, bv, qbf, kbf, vtb);
    flash_splitk<<<dim3(B_ * CHUNKS_PER_B), 256, 0, stream>>>(
        qbf, kbf, vtb, outp, part);
    combine<<<dim3(S_ / 64 - CK, B_, 4), 256, 0, stream>>>(part, outp);
}

// Round 10
// 173.488 us; speedup vs baseline: 2.3472x; 2.3472x over previous
//
#include <hip/hip_runtime.h>
#include <math.h>

#define B_   4
#define S_   4096
#define D_   1024
#define HD_  64

// ---------------- split-K flash constants ----------------
#define CK            8          // k-tiles (of 64 keys) per chunk
#define CHUNKS_PER_B  288        // sum_{qi=0}^{63} (qi/8 + 1)  (partial slots)
#define FULL_CHUNKS   224        // sum_{qi=0}^{63} (qi/8)      (8-iter chunks/batch)
// partials stored as bf16 (o[64]) + fp32 m,l -> 72 shorts (144 B) per row
#define PSTRIDE_SH    72         // shorts per row in a partial slot
#define SLOT_SH       (64 * PSTRIDE_SH)

// LESSONS LEDGER:
//  - R2: defer-max (T13) PERMANENTLY REVERTED (post-timing divergence).
//  - R5: hipLaunchCooperativeKernel dead under harness graph capture.
//  - R7: T_pipeline = 62.1 us; fixed harness overhead = 91.3 us (untouchable).
//  - R8 COUNTERS (flash, x8 surfaced): T_flash = 31.1 us, T_proj = 12.0 us
//    (proj ~at HBM floor). flash: MfmaUtil 11.8 / VALUBusy 48.5 / LDS ~40%
//    -> pipes SUM to ~100%: zero inter-wave overlap, Occupancy 22.7%.
//  - R9: compile error (helper used before decl). R9b = same kernel, fixed.
//    Occupancy attack: Q->regs (kill qsh), LDS [64][64]+XOR-swizzle
//    (24576 B -> 6 blocks/CU, was 36864 B -> 4), launch_bounds(256,6).
#define QSCALE   (0.125f * 1.44269504089f)

typedef float  f32x4  __attribute__((ext_vector_type(4)));
typedef __bf16 bf16x8 __attribute__((ext_vector_type(8)));
typedef __bf16 bf16x4 __attribute__((ext_vector_type(4)));

static __device__ __forceinline__ unsigned short bfbits(float f) {
    __bf16 h = (__bf16)f;
    return __builtin_bit_cast(unsigned short, h);
}

// hardware exp2: llvm.exp2.f32 lowers to a single v_exp_f32. exp2(-inf) = 0.
static __device__ __forceinline__ float exp2_hw(float x) {
    return __builtin_exp2f(x);
}

// slot index of (qi, c) within a batch: qi + sum_{j<qi}(j>>3) + c
static __device__ __forceinline__ int chunk_slot(int qi, int c) {
    const int a = qi >> 3, r = qi & 7;
    return qi + 4 * a * (a - 1) + a * r + c;
}

// ------------------------------------------------------------------
// Kernel 0: convert wq/wk/wv (fp32 [64][1024]) into wbf (bf16 [192][1024]).
// ------------------------------------------------------------------
__global__ __launch_bounds__(256) void convert_w(
    const float* __restrict__ wq, const float* __restrict__ wk,
    const float* __restrict__ wv, unsigned short* __restrict__ wbf)
{
    const int col = blockIdx.x;            // 0..191
    const int p = col >> 6, h = col & 63;
    const float* src = (p == 0 ? wq : (p == 1 ? wk : wv)) + (size_t)h * D_;
    const int t = threadIdx.x;
    const float4 v = ((const float4*)src)[t];
    bf16x4 o;
    o[0] = (__bf16)v.x; o[1] = (__bf16)v.y; o[2] = (__bf16)v.z; o[3] = (__bf16)v.w;
    *(bf16x4*)&wbf[(size_t)col * D_ + 4 * t] = o;
}

// ------------------------------------------------------------------
// Kernel 1: QKV projection via bf16 MFMA (16x16x32), BK=128.
// R6 body (measured ~12 us = near HBM floor). Unchanged.
// ------------------------------------------------------------------
__global__ __launch_bounds__(256) void proj_mfma(
    const float* __restrict__ x, const unsigned short* __restrict__ wbf,
    const float* __restrict__ bq, const float* __restrict__ bk,
    const float* __restrict__ bv,
    unsigned short* __restrict__ qbf, unsigned short* __restrict__ kbf,
    unsigned short* __restrict__ vtb)
{
    __shared__ unsigned short xs[32][136];    // 8704 B
    __shared__ unsigned short wsh[96][136];   // 26112 B

    const int t = threadIdx.x;
    const int w = t >> 6, lane = t & 63;
    const int n = lane & 15, g = lane >> 4;
    const int koff = 8 * g;
    const int rt = w & 1, cg = w >> 1;
    const size_t row0 = (size_t)blockIdx.x * 32;
    const int colbase = 96 * blockIdx.y;

    f32x4 acc[3];
#pragma unroll
    for (int i = 0; i < 3; ++i) acc[i] = (f32x4)0.f;

    for (int chunk = 0; chunk < 8; ++chunk) {
        const int d0 = chunk * 128;
        __syncthreads();
        // stage x: 32 rows x 128 d, fp32 -> bf16 (4 float4/thread)
#pragma unroll
        for (int i = 0; i < 4; ++i) {
            int e = t + i * 256;              // 0..1023 float4
            int r = e >> 5, c4 = (e & 31) * 4;
            float4 v = *(const float4*)&x[(row0 + r) * D_ + d0 + c4];
            bf16x4 o;
            o[0] = (__bf16)v.x; o[1] = (__bf16)v.y;
            o[2] = (__bf16)v.z; o[3] = (__bf16)v.w;
            *(bf16x4*)&xs[r][c4] = o;
        }
        // stage w: 96 cols x 128 d bf16 (6 uint4/thread)
#pragma unroll
        for (int i = 0; i < 6; ++i) {
            int e = t + i * 256;              // 0..1535
            int col = e >> 4, g8 = (e & 15) * 8;
            uint4 v = *(const uint4*)&wbf[(size_t)(colbase + col) * D_ + d0 + g8];
            *(uint4*)&wsh[col][g8] = v;
        }
        __syncthreads();

#pragma unroll
        for (int ks = 0; ks < 4; ++ks) {
            const int k0 = 32 * ks;
            const bf16x8 a = *(const bf16x8*)&xs[16 * rt + n][k0 + koff];
#pragma unroll
            for (int ci = 0; ci < 3; ++ci) {
                const bf16x8 b = *(const bf16x8*)&wsh[48 * cg + 16 * ci + n][k0 + koff];
                acc[ci] = __builtin_amdgcn_mfma_f32_16x16x32_bf16(a, b, acc[ci], 0, 0, 0);
            }
        }
    }

#pragma unroll
    for (int ci = 0; ci < 3; ++ci) {
        const int gct = 6 * blockIdx.y + 3 * cg + ci;
        const int p = gct >> 2, h0 = (gct & 3) * 16;
        const int h = h0 + n;
        const float bb = (p == 0 ? bq : (p == 1 ? bk : bv))[h];
        if (p == 2) {
            const size_t grow0 = row0 + 16 * rt + 4 * g;
            const int bidx = (int)(grow0 >> 12);
            const int s0 = (int)(grow0 & 4095);
            bf16x4 u;
            u[0] = (__bf16)(acc[ci][0] + bb); u[1] = (__bf16)(acc[ci][1] + bb);
            u[2] = (__bf16)(acc[ci][2] + bb); u[3] = (__bf16)(acc[ci][3] + bb);
            *(bf16x4*)&vtb[((size_t)bidx * HD_ + h) * S_ + s0] = u;
        } else {
            unsigned short* outp = (p == 0 ? qbf : kbf);
            const float scale = (p == 0) ? QSCALE : 1.0f;
#pragma unroll
            for (int r = 0; r < 4; ++r) {
                const size_t grow = row0 + 16 * rt + 4 * g + r;
                outp[grow * HD_ + h] = bfbits((acc[ci][r] + bb) * scale);
            }
        }
    }
}

// ------------------------------------------------------------------
// Kernel 2: split-K causal flash attention, bf16 MFMA.
// R9 occupancy attack:
//  - Q fragments in REGISTERS (wave-private, k-invariant) — no qsh.
//  - ksh/vsh/psh: [64][64] shorts (128 B rows) + XOR swizzle
//    chunk16 ^= (row & 7), applied identically on write AND read
//    (rule #21 both-sides; bijective per row).
//  - LDS 24576 B -> 6 blocks/CU (was 36864 -> 4). launch_bounds(256,6).
// ------------------------------------------------------------------
__global__ __launch_bounds__(256, 6) void flash_splitk(
    const unsigned short* __restrict__ qg, const unsigned short* __restrict__ kg,
    const unsigned short* __restrict__ vt, float* __restrict__ out,
    unsigned short* __restrict__ part)
{
    __shared__ unsigned short ksh[64 * 64];     // 8192 B  K rows (swizzled)
    __shared__ unsigned short vsh[64 * 64];     // 8192 B  vT[h][key] (swizzled)
    __shared__ unsigned short psh[4 * 16 * 64]; // 8192 B  per-wave P (swizzled)

    const int t    = threadIdx.x;
    const int w    = t >> 6;
    const int lane = t & 63;
    const int n    = lane & 15;      // MFMA col index
    const int g    = lane >> 4;      // MFMA row group
    const int nx   = n & 7;          // swizzle key for read rows (16mt+n)&7 == n&7

    // decode blockIdx.x -> (b, qi, c), full chunks first (tail fill)
    int b, qi, c;
    {
        const int idx = blockIdx.x;
        if (idx < B_ * FULL_CHUNKS) {          // full 8-iteration chunks
            b = idx / FULL_CHUNKS;
            int rem = idx - b * FULL_CHUNKS;
            qi = 8;
            while (rem >= (qi >> 3)) { rem -= (qi >> 3); ++qi; }
            c = rem;
        } else {                               // last (partial) chunk of each qi
            const int r2 = idx - B_ * FULL_CHUNKS;
            b = r2 >> 6;
            qi = r2 & 63;
            c = qi >> 3;
        }
    }
    const int kt0 = c * CK;
    const int kt1 = min(qi, kt0 + CK - 1);
    const int nc  = (qi >> 3) + 1;

    const size_t qtile = ((size_t)b * S_ + (size_t)qi * 64) * HD_;

    // Q fragments straight to registers (k-invariant; one 2-KB tile per block,
    // L2-resident). q8[ks] = Q[16w+n][32ks + 8g .. +7], pre-scaled w/ log2e.
    bf16x8 q8[2];
    {
        const unsigned short* qrow = qg + qtile + (size_t)(16 * w + n) * HD_ + 8 * g;
        q8[0] = *(const bf16x8*)&qrow[0];
        q8[1] = *(const bf16x8*)&qrow[32];
    }

    // staging coordinates (e0 = t, e1 = t+256), swizzled short offsets.
    // (t+256)&7 == t&7, so both elements share chunk index gg0.
    const int r0s = t >> 3,       gg0 = t & 7;
    const int r1s = r0s + 32;     // (t+256)>>3
    const int so0 = r0s * 64 + ((gg0 ^ (r0s & 7)) << 3);
    const int so1 = r1s * 64 + ((gg0 ^ (r1s & 7)) << 3);

    // T14 prologue: issue kt0's K/V global loads into registers
    uint4 kr0, kr1, vr0, vr1;
    {
        const size_t kvb = ((size_t)b * S_ + (size_t)kt0 * 64) * HD_;
        const uint4* ksrc = (const uint4*)(kg + kvb);
        kr0 = ksrc[t];
        kr1 = ksrc[t + 256];
        vr0 = *(const uint4*)&vt[((size_t)b * HD_ + r0s) * S_ + kt0 * 64 + 8 * gg0];
        vr1 = *(const uint4*)&vt[((size_t)b * HD_ + r1s) * S_ + kt0 * 64 + 8 * gg0];
    }

    f32x4 o4[4];                                 // O^T[h=16ht+4g+r][q=n]
#pragma unroll
    for (int i = 0; i < 4; ++i) o4[i] = (f32x4)0.f;
    float m_r = -INFINITY, l_r = 0.f;            // state of q = 16w+n (log2 domain)

    for (int kt = kt0; kt <= kt1; ++kt) {
        __syncthreads();                        // prev iteration's reads done
        // write the in-flight registers (compiler inserts vmcnt wait here)
        *(uint4*)&ksh[so0] = kr0;
        *(uint4*)&ksh[so1] = kr1;
        *(uint4*)&vsh[so0] = vr0;
        *(uint4*)&vsh[so1] = vr1;
        __syncthreads();

        // T14: issue NEXT tile's loads now; latency hides under this tile's compute
        if (kt < kt1) {
            const size_t kvb = ((size_t)b * S_ + (size_t)(kt + 1) * 64) * HD_;
            const uint4* ksrc = (const uint4*)(kg + kvb);
            kr0 = ksrc[t];
            kr1 = ksrc[t + 256];
            vr0 = *(const uint4*)&vt[((size_t)b * HD_ + r0s) * S_ + (kt + 1) * 64 + 8 * gg0];
            vr1 = *(const uint4*)&vt[((size_t)b * HD_ + r1s) * S_ + (kt + 1) * 64 + 8 * gg0];
        }

        // ---- S^T = K . Q^T : 4 m-tiles (keys) x 16 q (col = q = n) ----
        // read ksh row 16mt+n, chunk16 = 4ks+g, swz ^= nx
        f32x4 sc[4];
#pragma unroll
        for (int mt = 0; mt < 4; ++mt) sc[mt] = (f32x4)0.f;
#pragma unroll
        for (int ks = 0; ks < 2; ++ks) {
#pragma unroll
            for (int mt = 0; mt < 4; ++mt) {
                const bf16x8 ak = *(const bf16x8*)&ksh[1024 * mt + 64 * n
                                                      + (((4 * ks + g) ^ nx) << 3)];
                sc[mt] = __builtin_amdgcn_mfma_f32_16x16x32_bf16(ak, q8[ks], sc[mt], 0, 0, 0);
            }
        }

        // ---- causal mask (diagonal k-tile only) ----
        if (kt == qi) {
            const int qloc = 16 * w + n;
#pragma unroll
            for (int mt = 0; mt < 4; ++mt)
#pragma unroll
                for (int r = 0; r < 4; ++r) {
                    const int kloc = 16 * mt + 4 * g + r;
                    if (kloc > qloc) sc[mt][r] = -INFINITY;
                }
        }

        // ---- online softmax per column q (exp2 domain, always-rescale) ----
        float mx = -INFINITY;
#pragma unroll
        for (int mt = 0; mt < 4; ++mt)
#pragma unroll
            for (int r = 0; r < 4; ++r) mx = fmaxf(mx, sc[mt][r]);
        mx = fmaxf(mx, __shfl_xor(mx, 16));
        mx = fmaxf(mx, __shfl_xor(mx, 32));

        const float m_new = fmaxf(m_r, mx);
        const float alpha = exp2_hw(m_r - m_new);   // first iter: exp2(-inf)=0
        float psum = 0.f;
#pragma unroll
        for (int mt = 0; mt < 4; ++mt)
#pragma unroll
            for (int r = 0; r < 4; ++r) {
                const float pe = exp2_hw(sc[mt][r] - m_new);
                sc[mt][r] = pe;
                psum += pe;
            }
        psum += __shfl_xor(psum, 16);
        psum += __shfl_xor(psum, 32);
        l_r = l_r * alpha + psum;
        m_r = m_new;

        // rescale O (all regs have col q = n -> alpha is in-lane)
#pragma unroll
        for (int ht = 0; ht < 4; ++ht)
#pragma unroll
            for (int r = 0; r < 4; ++r) o4[ht][r] *= alpha;

        // ---- pack P^T -> per-wave LDS p[q][key], swizzled ----
        // element 16mt+4g -> chunk16 = 2mt + (g>>1), sub-off (g&1)*4, swz ^= nx
#pragma unroll
        for (int mt = 0; mt < 4; ++mt) {
            bf16x4 u;
            u[0] = (__bf16)sc[mt][0]; u[1] = (__bf16)sc[mt][1];
            u[2] = (__bf16)sc[mt][2]; u[3] = (__bf16)sc[mt][3];
            *(bf16x4*)&psh[1024 * w + 64 * n + (((2 * mt + (g >> 1)) ^ nx) << 3)
                           + ((g & 1) << 2)] = u;
        }
        // same-wave RAW on LDS: compiler inserts lgkmcnt wait; no barrier needed

        // ---- O^T += vT . P^T  (A = vT rows, B = P^T; swizzled reads) ----
#pragma unroll
        for (int ks = 0; ks < 2; ++ks) {
            const bf16x8 ap = *(const bf16x8*)&psh[1024 * w + 64 * n
                                                   + (((4 * ks + g) ^ nx) << 3)];
#pragma unroll
            for (int ht = 0; ht < 4; ++ht) {
                const bf16x8 av = *(const bf16x8*)&vsh[1024 * ht + 64 * n
                                                       + (((4 * ks + g) ^ nx) << 3)];
                o4[ht] = __builtin_amdgcn_mfma_f32_16x16x32_bf16(av, ap, o4[ht], 0, 0, 0);
            }
        }
    }

    const size_t qbase = ((size_t)b * S_ + (size_t)qi * 64) * HD_;
    if (nc == 1) {
        const float inv = 1.f / l_r;             // in-lane (q = 16w+n)
        const size_t ob = qbase + (size_t)(16 * w + n) * HD_;
#pragma unroll
        for (int ht = 0; ht < 4; ++ht) {
            float4 rv;
            rv.x = o4[ht][0] * inv; rv.y = o4[ht][1] * inv;
            rv.z = o4[ht][2] * inv; rv.w = o4[ht][3] * inv;
            *(float4*)&out[ob + 16 * ht + 4 * g] = rv;
        }
    } else {
        // partial slot row (q = 16w+n): o[64] bf16, then m,l fp32 at shorts 64/66
        const size_t sb = ((size_t)b * CHUNKS_PER_B + chunk_slot(qi, c)) * SLOT_SH;
        const size_t pb = sb + (size_t)(16 * w + n) * PSTRIDE_SH;
#pragma unroll
        for (int ht = 0; ht < 4; ++ht) {
            bf16x4 u;
            u[0] = (__bf16)o4[ht][0]; u[1] = (__bf16)o4[ht][1];
            u[2] = (__bf16)o4[ht][2]; u[3] = (__bf16)o4[ht][3];
            *(bf16x4*)&part[pb + 16 * ht + 4 * g] = u;
        }
        if (g == 0) {
            *(float*)&part[pb + 64] = m_r;       // log2-domain running max
            *(float*)&part[pb + 66] = l_r;
        }
    }
}

// ------------------------------------------------------------------
// Kernel 3: merge partials for qi >= CK.  grid (56, B, 4) — R4 exact.
// ------------------------------------------------------------------
__global__ __launch_bounds__(256) void combine(
    const unsigned short* __restrict__ part, float* __restrict__ out)
{
    const int t  = threadIdx.x;
    const int qr = t >> 2, tc = t & 3;
    const int qi = blockIdx.x + CK;          // 8..63
    const int b  = blockIdx.y;
    const int hq = blockIdx.z;               // 0..3 -> h block of 16
    const int nc = (qi >> 3) + 1;

    const size_t base0 = ((size_t)b * CHUNKS_PER_B + chunk_slot(qi, 0)) * SLOT_SH
                       + (size_t)qr * PSTRIDE_SH;

    float M = -INFINITY;
    for (int c0 = 0; c0 < nc; ++c0)
        M = fmaxf(M, *(const float*)&part[base0 + (size_t)c0 * SLOT_SH + 64]);

    float L = 0.f;
    float o[4];
#pragma unroll
    for (int j = 0; j < 4; ++j) o[j] = 0.f;

    const int ho = hq * 16 + tc * 4;         // this thread's 4 heads

    for (int c0 = 0; c0 < nc; ++c0) {
        const size_t sb = base0 + (size_t)c0 * SLOT_SH;
        const float m_c = *(const float*)&part[sb + 64];
        const float l_c = *(const float*)&part[sb + 66];
        const float w = exp2_hw(m_c - M);
        L += w * l_c;
        const bf16x4 ov = *(const bf16x4*)&part[sb + ho];
#pragma unroll
        for (int j = 0; j < 4; ++j) o[j] += w * (float)ov[j];
    }

    const float inv = 1.f / L;
    const size_t ob = ((size_t)b * S_ + (size_t)qi * 64 + qr) * HD_ + ho;
    float4 r;
    r.x = o[0] * inv; r.y = o[1] * inv; r.z = o[2] * inv; r.w = o[3] * inv;
    *(float4*)&out[ob] = r;
}

// ------------------------------------------------------------------
extern "C" void kernel_launch(void* const* d_in, const int* in_sizes, int n_in,
                              void* d_out, int out_size, void* d_ws, size_t ws_size,
                              hipStream_t stream)
{
    const float* x  = (const float*)d_in[0];
    const float* wq = (const float*)d_in[1];
    const float* bq = (const float*)d_in[2];
    const float* wk = (const float*)d_in[3];
    const float* bk = (const float*)d_in[4];
    const float* wv = (const float*)d_in[5];
    const float* bv = (const float*)d_in[6];
    float* outp = (float*)d_out;

    // ws layout: qbf | kbf | vt (bf16, n each) | wbf (bf16) | part (bf16+fp32 m,l)
    const size_t n = (size_t)B_ * S_ * HD_;        // 1048576
    unsigned short* qbf = (unsigned short*)d_ws;
    unsigned short* kbf = qbf + n;
    unsigned short* vtb = kbf + n;
    unsigned short* wbf = vtb + n;                 // 192*1024 bf16
    unsigned short* part = wbf + (size_t)192 * D_; // 4*288*4608 shorts = 10.6 MB

    convert_w<<<dim3(192), 256, 0, stream>>>(wq, wk, wv, wbf);
    proj_mfma<<<dim3(B_ * S_ / 32, 2), 256, 0, stream>>>(
        x, wbf, bq, bk, bv, qbf, kbf, vtb);
    flash_splitk<<<dim3(B_ * CHUNKS_PER_B), 256, 0, stream>>>(
        qbf, kbf, vtb, outp, part);
    combine<<<dim3(S_ / 64 - CK, B_, 4), 256, 0, stream>>>(part, outp);
}

// Round 11
// 149.936 us; speedup vs baseline: 2.7159x; 1.1571x over previous
//
#include <hip/hip_runtime.h>
#include <math.h>

#define B_   4
#define S_   4096
#define D_   1024
#define HD_  64

// ---------------- split-K flash constants ----------------
#define CK            8          // k-tiles (of 64 keys) per chunk
#define CHUNKS_PER_B  288        // sum_{qi=0}^{63} (qi/8 + 1)  (partial slots)
#define FULL_CHUNKS   224        // sum_{qi=0}^{63} (qi/8)      (8-iter chunks/batch)
// partials stored as bf16 (o[64]) + fp32 m,l -> 72 shorts (144 B) per row
#define PSTRIDE_SH    72         // shorts per row in a partial slot
#define SLOT_SH       (64 * PSTRIDE_SH)

// LESSONS LEDGER:
//  - R2: defer-max (T13) PERMANENTLY REVERTED (post-timing divergence).
//  - R5: hipLaunchCooperativeKernel dead under harness graph capture.
//  - R7: T_pipeline = 62.1 us; fixed harness overhead = 91.3 us (untouchable).
//  - R8 COUNTERS: T_flash = 31.1 us @ VGPR 68, 16 waves/CU; pipes sum ~100%.
//  - R10: launch_bounds(256,6) forced VGPR 40 < live set -> SCRATCH SPILLS
//    (WRITE_SIZE 81 MB, all pipes idle, flash 54 us). VGPR quantizes at
//    64/128/256: >16 waves/CU requires VGPR <= 64 WITHOUT spilling.
//    Swizzle verified good: bank conflicts 2.56e7 -> 5.3e5.
//  - R11: drop T14 prefetch regs (-16 live, was neutral in R6 anyway);
//    live set ~56-62 -> launch_bounds(256,8) targets VGPR<=64 cleanly.
//    LDS 24576 B -> 6 blocks/CU = 24 waves/CU.
#define QSCALE   (0.125f * 1.44269504089f)

typedef float  f32x4  __attribute__((ext_vector_type(4)));
typedef __bf16 bf16x8 __attribute__((ext_vector_type(8)));
typedef __bf16 bf16x4 __attribute__((ext_vector_type(4)));

static __device__ __forceinline__ unsigned short bfbits(float f) {
    __bf16 h = (__bf16)f;
    return __builtin_bit_cast(unsigned short, h);
}

// hardware exp2: llvm.exp2.f32 lowers to a single v_exp_f32. exp2(-inf) = 0.
static __device__ __forceinline__ float exp2_hw(float x) {
    return __builtin_exp2f(x);
}

// slot index of (qi, c) within a batch: qi + sum_{j<qi}(j>>3) + c
static __device__ __forceinline__ int chunk_slot(int qi, int c) {
    const int a = qi >> 3, r = qi & 7;
    return qi + 4 * a * (a - 1) + a * r + c;
}

// ------------------------------------------------------------------
// Kernel 0: convert wq/wk/wv (fp32 [64][1024]) into wbf (bf16 [192][1024]).
// ------------------------------------------------------------------
__global__ __launch_bounds__(256) void convert_w(
    const float* __restrict__ wq, const float* __restrict__ wk,
    const float* __restrict__ wv, unsigned short* __restrict__ wbf)
{
    const int col = blockIdx.x;            // 0..191
    const int p = col >> 6, h = col & 63;
    const float* src = (p == 0 ? wq : (p == 1 ? wk : wv)) + (size_t)h * D_;
    const int t = threadIdx.x;
    const float4 v = ((const float4*)src)[t];
    bf16x4 o;
    o[0] = (__bf16)v.x; o[1] = (__bf16)v.y; o[2] = (__bf16)v.z; o[3] = (__bf16)v.w;
    *(bf16x4*)&wbf[(size_t)col * D_ + 4 * t] = o;
}

// ------------------------------------------------------------------
// Kernel 1: QKV projection via bf16 MFMA (16x16x32), BK=128.
// R6 body (measured ~12 us = near HBM floor). Unchanged.
// ------------------------------------------------------------------
__global__ __launch_bounds__(256) void proj_mfma(
    const float* __restrict__ x, const unsigned short* __restrict__ wbf,
    const float* __restrict__ bq, const float* __restrict__ bk,
    const float* __restrict__ bv,
    unsigned short* __restrict__ qbf, unsigned short* __restrict__ kbf,
    unsigned short* __restrict__ vtb)
{
    __shared__ unsigned short xs[32][136];    // 8704 B
    __shared__ unsigned short wsh[96][136];   // 26112 B

    const int t = threadIdx.x;
    const int w = t >> 6, lane = t & 63;
    const int n = lane & 15, g = lane >> 4;
    const int koff = 8 * g;
    const int rt = w & 1, cg = w >> 1;
    const size_t row0 = (size_t)blockIdx.x * 32;
    const int colbase = 96 * blockIdx.y;

    f32x4 acc[3];
#pragma unroll
    for (int i = 0; i < 3; ++i) acc[i] = (f32x4)0.f;

    for (int chunk = 0; chunk < 8; ++chunk) {
        const int d0 = chunk * 128;
        __syncthreads();
        // stage x: 32 rows x 128 d, fp32 -> bf16 (4 float4/thread)
#pragma unroll
        for (int i = 0; i < 4; ++i) {
            int e = t + i * 256;              // 0..1023 float4
            int r = e >> 5, c4 = (e & 31) * 4;
            float4 v = *(const float4*)&x[(row0 + r) * D_ + d0 + c4];
            bf16x4 o;
            o[0] = (__bf16)v.x; o[1] = (__bf16)v.y;
            o[2] = (__bf16)v.z; o[3] = (__bf16)v.w;
            *(bf16x4*)&xs[r][c4] = o;
        }
        // stage w: 96 cols x 128 d bf16 (6 uint4/thread)
#pragma unroll
        for (int i = 0; i < 6; ++i) {
            int e = t + i * 256;              // 0..1535
            int col = e >> 4, g8 = (e & 15) * 8;
            uint4 v = *(const uint4*)&wbf[(size_t)(colbase + col) * D_ + d0 + g8];
            *(uint4*)&wsh[col][g8] = v;
        }
        __syncthreads();

#pragma unroll
        for (int ks = 0; ks < 4; ++ks) {
            const int k0 = 32 * ks;
            const bf16x8 a = *(const bf16x8*)&xs[16 * rt + n][k0 + koff];
#pragma unroll
            for (int ci = 0; ci < 3; ++ci) {
                const bf16x8 b = *(const bf16x8*)&wsh[48 * cg + 16 * ci + n][k0 + koff];
                acc[ci] = __builtin_amdgcn_mfma_f32_16x16x32_bf16(a, b, acc[ci], 0, 0, 0);
            }
        }
    }

#pragma unroll
    for (int ci = 0; ci < 3; ++ci) {
        const int gct = 6 * blockIdx.y + 3 * cg + ci;
        const int p = gct >> 2, h0 = (gct & 3) * 16;
        const int h = h0 + n;
        const float bb = (p == 0 ? bq : (p == 1 ? bk : bv))[h];
        if (p == 2) {
            const size_t grow0 = row0 + 16 * rt + 4 * g;
            const int bidx = (int)(grow0 >> 12);
            const int s0 = (int)(grow0 & 4095);
            bf16x4 u;
            u[0] = (__bf16)(acc[ci][0] + bb); u[1] = (__bf16)(acc[ci][1] + bb);
            u[2] = (__bf16)(acc[ci][2] + bb); u[3] = (__bf16)(acc[ci][3] + bb);
            *(bf16x4*)&vtb[((size_t)bidx * HD_ + h) * S_ + s0] = u;
        } else {
            unsigned short* outp = (p == 0 ? qbf : kbf);
            const float scale = (p == 0) ? QSCALE : 1.0f;
#pragma unroll
            for (int r = 0; r < 4; ++r) {
                const size_t grow = row0 + 16 * rt + 4 * g + r;
                outp[grow * HD_ + h] = bfbits((acc[ci][r] + bb) * scale);
            }
        }
    }
}

// ------------------------------------------------------------------
// Kernel 2: split-K causal flash attention, bf16 MFMA.
// R11: Q-in-regs + swizzled 24 KB LDS (R9) with the spill fixed:
//  - NO cross-tile prefetch (T14 dropped; neutral in R6, frees 16 VGPR).
//    Loads for tile kt issue BEFORE barrier #1 (no LDS dependency ->
//    barrier doesn't drain them; latency hides under prev compute tail
//    + 24 waves/CU of TLP).
//  - launch_bounds(256,8): VGPR <= 64 (live set ~56-62, fits cleanly).
// ------------------------------------------------------------------
__global__ __launch_bounds__(256, 8) void flash_splitk(
    const unsigned short* __restrict__ qg, const unsigned short* __restrict__ kg,
    const unsigned short* __restrict__ vt, float* __restrict__ out,
    unsigned short* __restrict__ part)
{
    __shared__ unsigned short ksh[64 * 64];     // 8192 B  K rows (swizzled)
    __shared__ unsigned short vsh[64 * 64];     // 8192 B  vT[h][key] (swizzled)
    __shared__ unsigned short psh[4 * 16 * 64]; // 8192 B  per-wave P (swizzled)

    const int t    = threadIdx.x;
    const int w    = t >> 6;
    const int lane = t & 63;
    const int n    = lane & 15;      // MFMA col index
    const int g    = lane >> 4;      // MFMA row group
    const int nx   = n & 7;          // swizzle key for read rows (16mt+n)&7 == n&7

    // decode blockIdx.x -> (b, qi, c), full chunks first (tail fill)
    int b, qi, c;
    {
        const int idx = blockIdx.x;
        if (idx < B_ * FULL_CHUNKS) {          // full 8-iteration chunks
            b = idx / FULL_CHUNKS;
            int rem = idx - b * FULL_CHUNKS;
            qi = 8;
            while (rem >= (qi >> 3)) { rem -= (qi >> 3); ++qi; }
            c = rem;
        } else {                               // last (partial) chunk of each qi
            const int r2 = idx - B_ * FULL_CHUNKS;
            b = r2 >> 6;
            qi = r2 & 63;
            c = qi >> 3;
        }
    }
    const int kt0 = c * CK;
    const int kt1 = min(qi, kt0 + CK - 1);
    const int nc  = (qi >> 3) + 1;

    const size_t qtile = ((size_t)b * S_ + (size_t)qi * 64) * HD_;

    // Q fragments straight to registers (k-invariant; 2-KB tile, L2-resident).
    // q8[ks] = Q[16w+n][32ks + 8g .. +7], pre-scaled w/ log2e.
    bf16x8 q8[2];
    {
        const unsigned short* qrow = qg + qtile + (size_t)(16 * w + n) * HD_ + 8 * g;
        q8[0] = *(const bf16x8*)&qrow[0];
        q8[1] = *(const bf16x8*)&qrow[32];
    }

    // staging coordinates (e0 = t, e1 = t+256), swizzled short offsets.
    // (t+256)&7 == t&7, so both elements share chunk index gg0.
    const int r0s = t >> 3,       gg0 = t & 7;
    const int r1s = r0s + 32;     // (t+256)>>3
    const int so0 = r0s * 64 + ((gg0 ^ (r0s & 7)) << 3);
    const int so1 = r1s * 64 + ((gg0 ^ (r1s & 7)) << 3);

    f32x4 o4[4];                                 // O^T[h=16ht+4g+r][q=n]
#pragma unroll
    for (int i = 0; i < 4; ++i) o4[i] = (f32x4)0.f;
    float m_r = -INFINITY, l_r = 0.f;            // state of q = 16w+n (log2 domain)

    for (int kt = kt0; kt <= kt1; ++kt) {
        // issue this tile's loads BEFORE the barrier (no LDS dependency):
        // latency overlaps prev tile's compute tail + barrier wait.
        const size_t kvb = ((size_t)b * S_ + (size_t)kt * 64) * HD_;
        const uint4* ksrc = (const uint4*)(kg + kvb);
        const uint4 kr0 = ksrc[t];
        const uint4 kr1 = ksrc[t + 256];
        const uint4 vr0 = *(const uint4*)&vt[((size_t)b * HD_ + r0s) * S_ + kt * 64 + 8 * gg0];
        const uint4 vr1 = *(const uint4*)&vt[((size_t)b * HD_ + r1s) * S_ + kt * 64 + 8 * gg0];

        __syncthreads();                        // prev iteration's reads done
        *(uint4*)&ksh[so0] = kr0;
        *(uint4*)&ksh[so1] = kr1;
        *(uint4*)&vsh[so0] = vr0;
        *(uint4*)&vsh[so1] = vr1;
        __syncthreads();

        // ---- S^T = K . Q^T : 4 m-tiles (keys) x 16 q (col = q = n) ----
        // read ksh row 16mt+n, chunk16 = 4ks+g, swz ^= nx
        f32x4 sc[4];
#pragma unroll
        for (int mt = 0; mt < 4; ++mt) sc[mt] = (f32x4)0.f;
#pragma unroll
        for (int ks = 0; ks < 2; ++ks) {
#pragma unroll
            for (int mt = 0; mt < 4; ++mt) {
                const bf16x8 ak = *(const bf16x8*)&ksh[1024 * mt + 64 * n
                                                      + (((4 * ks + g) ^ nx) << 3)];
                sc[mt] = __builtin_amdgcn_mfma_f32_16x16x32_bf16(ak, q8[ks], sc[mt], 0, 0, 0);
            }
        }

        // ---- causal mask (diagonal k-tile only) ----
        if (kt == qi) {
            const int qloc = 16 * w + n;
#pragma unroll
            for (int mt = 0; mt < 4; ++mt)
#pragma unroll
                for (int r = 0; r < 4; ++r) {
                    const int kloc = 16 * mt + 4 * g + r;
                    if (kloc > qloc) sc[mt][r] = -INFINITY;
                }
        }

        // ---- online softmax per column q (exp2 domain, always-rescale) ----
        float mx = -INFINITY;
#pragma unroll
        for (int mt = 0; mt < 4; ++mt)
#pragma unroll
            for (int r = 0; r < 4; ++r) mx = fmaxf(mx, sc[mt][r]);
        mx = fmaxf(mx, __shfl_xor(mx, 16));
        mx = fmaxf(mx, __shfl_xor(mx, 32));

        const float m_new = fmaxf(m_r, mx);
        const float alpha = exp2_hw(m_r - m_new);   // first iter: exp2(-inf)=0
        float psum = 0.f;
#pragma unroll
        for (int mt = 0; mt < 4; ++mt)
#pragma unroll
            for (int r = 0; r < 4; ++r) {
                const float pe = exp2_hw(sc[mt][r] - m_new);
                sc[mt][r] = pe;
                psum += pe;
            }
        psum += __shfl_xor(psum, 16);
        psum += __shfl_xor(psum, 32);
        l_r = l_r * alpha + psum;
        m_r = m_new;

        // rescale O (all regs have col q = n -> alpha is in-lane)
#pragma unroll
        for (int ht = 0; ht < 4; ++ht)
#pragma unroll
            for (int r = 0; r < 4; ++r) o4[ht][r] *= alpha;

        // ---- pack P^T -> per-wave LDS p[q][key], swizzled ----
        // element 16mt+4g -> chunk16 = 2mt + (g>>1), sub-off (g&1)*4, swz ^= nx
#pragma unroll
        for (int mt = 0; mt < 4; ++mt) {
            bf16x4 u;
            u[0] = (__bf16)sc[mt][0]; u[1] = (__bf16)sc[mt][1];
            u[2] = (__bf16)sc[mt][2]; u[3] = (__bf16)sc[mt][3];
            *(bf16x4*)&psh[1024 * w + 64 * n + (((2 * mt + (g >> 1)) ^ nx) << 3)
                           + ((g & 1) << 2)] = u;
        }
        // same-wave RAW on LDS: compiler inserts lgkmcnt wait; no barrier needed

        // ---- O^T += vT . P^T  (A = vT rows, B = P^T; swizzled reads) ----
#pragma unroll
        for (int ks = 0; ks < 2; ++ks) {
            const bf16x8 ap = *(const bf16x8*)&psh[1024 * w + 64 * n
                                                   + (((4 * ks + g) ^ nx) << 3)];
#pragma unroll
            for (int ht = 0; ht < 4; ++ht) {
                const bf16x8 av = *(const bf16x8*)&vsh[1024 * ht + 64 * n
                                                       + (((4 * ks + g) ^ nx) << 3)];
                o4[ht] = __builtin_amdgcn_mfma_f32_16x16x32_bf16(av, ap, o4[ht], 0, 0, 0);
            }
        }
    }

    const size_t qbase = ((size_t)b * S_ + (size_t)qi * 64) * HD_;
    if (nc == 1) {
        const float inv = 1.f / l_r;             // in-lane (q = 16w+n)
        const size_t ob = qbase + (size_t)(16 * w + n) * HD_;
#pragma unroll
        for (int ht = 0; ht < 4; ++ht) {
            float4 rv;
            rv.x = o4[ht][0] * inv; rv.y = o4[ht][1] * inv;
            rv.z = o4[ht][2] * inv; rv.w = o4[ht][3] * inv;
            *(float4*)&out[ob + 16 * ht + 4 * g] = rv;
        }
    } else {
        // partial slot row (q = 16w+n): o[64] bf16, then m,l fp32 at shorts 64/66
        const size_t sb = ((size_t)b * CHUNKS_PER_B + chunk_slot(qi, c)) * SLOT_SH;
        const size_t pb = sb + (size_t)(16 * w + n) * PSTRIDE_SH;
#pragma unroll
        for (int ht = 0; ht < 4; ++ht) {
            bf16x4 u;
            u[0] = (__bf16)o4[ht][0]; u[1] = (__bf16)o4[ht][1];
            u[2] = (__bf16)o4[ht][2]; u[3] = (__bf16)o4[ht][3];
            *(bf16x4*)&part[pb + 16 * ht + 4 * g] = u;
        }
        if (g == 0) {
            *(float*)&part[pb + 64] = m_r;       // log2-domain running max
            *(float*)&part[pb + 66] = l_r;
        }
    }
}

// ------------------------------------------------------------------
// Kernel 3: merge partials for qi >= CK.  grid (56, B, 4) — R4 exact.
// ------------------------------------------------------------------
__global__ __launch_bounds__(256) void combine(
    const unsigned short* __restrict__ part, float* __restrict__ out)
{
    const int t  = threadIdx.x;
    const int qr = t >> 2, tc = t & 3;
    const int qi = blockIdx.x + CK;          // 8..63
    const int b  = blockIdx.y;
    const int hq = blockIdx.z;               // 0..3 -> h block of 16
    const int nc = (qi >> 3) + 1;

    const size_t base0 = ((size_t)b * CHUNKS_PER_B + chunk_slot(qi, 0)) * SLOT_SH
                       + (size_t)qr * PSTRIDE_SH;

    float M = -INFINITY;
    for (int c0 = 0; c0 < nc; ++c0)
        M = fmaxf(M, *(const float*)&part[base0 + (size_t)c0 * SLOT_SH + 64]);

    float L = 0.f;
    float o[4];
#pragma unroll
    for (int j = 0; j < 4; ++j) o[j] = 0.f;

    const int ho = hq * 16 + tc * 4;         // this thread's 4 heads

    for (int c0 = 0; c0 < nc; ++c0) {
        const size_t sb = base0 + (size_t)c0 * SLOT_SH;
        const float m_c = *(const float*)&part[sb + 64];
        const float l_c = *(const float*)&part[sb + 66];
        const float w = exp2_hw(m_c - M);
        L += w * l_c;
        const bf16x4 ov = *(const bf16x4*)&part[sb + ho];
#pragma unroll
        for (int j = 0; j < 4; ++j) o[j] += w * (float)ov[j];
    }

    const float inv = 1.f / L;
    const size_t ob = ((size_t)b * S_ + (size_t)qi * 64 + qr) * HD_ + ho;
    float4 r;
    r.x = o[0] * inv; r.y = o[1] * inv; r.z = o[2] * inv; r.w = o[3] * inv;
    *(float4*)&out[ob] = r;
}

// ------------------------------------------------------------------
extern "C" void kernel_launch(void* const* d_in, const int* in_sizes, int n_in,
                              void* d_out, int out_size, void* d_ws, size_t ws_size,
                              hipStream_t stream)
{
    const float* x  = (const float*)d_in[0];
    const float* wq = (const float*)d_in[1];
    const float* bq = (const float*)d_in[2];
    const float* wk = (const float*)d_in[3];
    const float* bk = (const float*)d_in[4];
    const float* wv = (const float*)d_in[5];
    const float* bv = (const float*)d_in[6];
    float* outp = (float*)d_out;

    // ws layout: qbf | kbf | vt (bf16, n each) | wbf (bf16) | part (bf16+fp32 m,l)
    const size_t n = (size_t)B_ * S_ * HD_;        // 1048576
    unsigned short* qbf = (unsigned short*)d_ws;
    unsigned short* kbf = qbf + n;
    unsigned short* vtb = kbf + n;
    unsigned short* wbf = vtb + n;                 // 192*1024 bf16
    unsigned short* part = wbf + (size_t)192 * D_; // 4*288*4608 shorts = 10.6 MB

    convert_w<<<dim3(192), 256, 0, stream>>>(wq, wk, wv, wbf);
    proj_mfma<<<dim3(B_ * S_ / 32, 2), 256, 0, stream>>>(
        x, wbf, bq, bk, bv, qbf, kbf, vtb);
    flash_splitk<<<dim3(B_ * CHUNKS_PER_B), 256, 0, stream>>>(
        qbf, kbf, vtb, outp, part);
    combine<<<dim3(S_ / 64 - CK, B_, 4), 256, 0, stream>>>(part, outp);
}